// Round 1
// baseline (223.378 us; speedup 1.0000x reference)
//
#include <hip/hip_runtime.h>
#include <hip/hip_bf16.h>

#define T_SEQ 2048
#define NH 16
#define HD 64

typedef __attribute__((ext_vector_type(8))) short bf16x8;
typedef __attribute__((ext_vector_type(4))) short bf16x4;
typedef __attribute__((ext_vector_type(4))) float f32x4;

__device__ __forceinline__ short f2bs(float f) {
  union { float f; unsigned u; } v; v.f = f;
  unsigned r = v.u + 0x7fffu + ((v.u >> 16) & 1u);
  return (short)(r >> 16);
}

// ---------------- f32 -> bf16 convert ----------------
__global__ __launch_bounds__(256) void cvt_bf16(const float* __restrict__ src,
                                                short* __restrict__ dst, int n) {
  int i = (blockIdx.x * 256 + threadIdx.x) * 4;
  if (i >= n) return;
  float4 v = *reinterpret_cast<const float4*>(src + i);
  bf16x4 o; o[0] = f2bs(v.x); o[1] = f2bs(v.y); o[2] = f2bs(v.z); o[3] = f2bs(v.w);
  *reinterpret_cast<bf16x4*>(dst + i) = o;
}

// ---------------- gate: sigmoid(x[:, :12] @ Wgate^T) ----------------
__global__ __launch_bounds__(256) void gate_kernel(const float* __restrict__ x,
                                                   const float* __restrict__ Wg,
                                                   float* __restrict__ gate) {
  int id = blockIdx.x * 256 + threadIdx.x;  // t*16 + h, exact grid
  int t = id >> 4, h = id & 15;
  float acc = 0.f;
  #pragma unroll
  for (int i = 0; i < 12; ++i) acc += x[(size_t)t * 1024 + i] * Wg[h * 12 + i];
  gate[id] = 1.f / (1.f + __expf(-acc));
}

// ---------------- GEMM: C[M][N] = A[M][K] * B[N][K]^T (bf16 in, f32 out) ----------------
// 128x128 tile, BK=32, 4 waves (2x2), each wave 64x64 via 4x4 16x16x32 MFMAs.
// LDS layout [kslot][row][8]: fragment read = one aligned ds_read_b128.
__global__ __launch_bounds__(256) void gemm_bt(const short* __restrict__ A,
                                               const short* __restrict__ B,
                                               float* __restrict__ C,
                                               int M, int N, int K) {
  __shared__ __attribute__((aligned(16))) short As[4][128][8];
  __shared__ __attribute__((aligned(16))) short Bs[4][128][8];
  const int tid = threadIdx.x;
  const int lane = tid & 63, wid = tid >> 6;
  const int lr = lane & 15, lg = lane >> 4;
  const int wm = (wid >> 1) * 64, wn = (wid & 1) * 64;
  const int bm = blockIdx.x * 128, bn = blockIdx.y * 128;
  const int r0 = tid >> 2, c0 = (tid & 3) * 8, ks = tid & 3;
  const short* Ap = A + (size_t)(bm + r0) * K + c0;
  const short* Bp = B + (size_t)(bn + r0) * K + c0;
  f32x4 acc[4][4] = {};
  for (int k0 = 0; k0 < K; k0 += 32) {
    bf16x8 a0 = *(const bf16x8*)(Ap + k0);
    bf16x8 a1 = *(const bf16x8*)(Ap + (size_t)64 * K + k0);
    bf16x8 b0 = *(const bf16x8*)(Bp + k0);
    bf16x8 b1 = *(const bf16x8*)(Bp + (size_t)64 * K + k0);
    __syncthreads();
    *(bf16x8*)&As[ks][r0][0] = a0;
    *(bf16x8*)&As[ks][64 + r0][0] = a1;
    *(bf16x8*)&Bs[ks][r0][0] = b0;
    *(bf16x8*)&Bs[ks][64 + r0][0] = b1;
    __syncthreads();
    bf16x8 af[4], bfr[4];
    #pragma unroll
    for (int m = 0; m < 4; ++m) af[m] = *(const bf16x8*)&As[lg][wm + m * 16 + lr][0];
    #pragma unroll
    for (int n = 0; n < 4; ++n) bfr[n] = *(const bf16x8*)&Bs[lg][wn + n * 16 + lr][0];
    #pragma unroll
    for (int m = 0; m < 4; ++m)
      #pragma unroll
      for (int n = 0; n < 4; ++n)
        acc[m][n] = __builtin_amdgcn_mfma_f32_16x16x32_bf16(af[m], bfr[n], acc[m][n], 0, 0, 0);
  }
  #pragma unroll
  for (int m = 0; m < 4; ++m) {
    const int row = bm + wm + m * 16 + 4 * lg;
    #pragma unroll
    for (int r = 0; r < 4; ++r) {
      float* Cr = C + (size_t)(row + r) * N + bn + wn + lr;
      #pragma unroll
      for (int n = 0; n < 4; ++n) Cr[n * 16] = acc[m][n][r];
    }
  }
}

// ---------------- q/k RMSNorm + RoPE (one wave per (t,h)) ----------------
__global__ __launch_bounds__(256) void qk_norm_rope(const float* __restrict__ Cq,
                                                    short* __restrict__ qb,
                                                    short* __restrict__ kb) {
  int wgid = blockIdx.x * 4 + (threadIdx.x >> 6);
  int lane = threadIdx.x & 63;
  int t = wgid >> 4, h = wgid & 15;
  float qv = Cq[(size_t)t * 3072 + h * 64 + lane];
  float kv = Cq[(size_t)t * 3072 + 1024 + h * 64 + lane];
  float sq = qv * qv, sk = kv * kv;
  #pragma unroll
  for (int o = 1; o < 64; o <<= 1) { sq += __shfl_xor(sq, o); sk += __shfl_xor(sk, o); }
  qv *= rsqrtf(sq * (1.f / 64.f) + 1e-6f);
  kv *= rsqrtf(sk * (1.f / 64.f) + 1e-6f);
  int p = lane & 31;
  float ang = (float)t * powf(10000.f, -(float)p * (1.f / 32.f));
  float s, c;
  sincosf(ang, &s, &c);
  float qo = __shfl_xor(qv, 32), ko = __shfl_xor(kv, 32);
  // ref: y1 = x1*cos + x2*sin ; y2 = -x1*sin + x2*cos
  float qr = (lane < 32) ? (qv * c + qo * s) : (qv * c - qo * s);
  float kr = (lane < 32) ? (kv * c + ko * s) : (kv * c - ko * s);
  qb[((size_t)h * T_SEQ + t) * 64 + lane] = f2bs(qr);
  kb[((size_t)h * T_SEQ + t) * 64 + lane] = f2bs(kr);
}

// ---------------- v blend + transpose to vt[h][hd][t] ----------------
__global__ __launch_bounds__(256) void v_blend_tr(const float* __restrict__ Cq,
                                                  const float* __restrict__ v1,
                                                  const float* __restrict__ lambp,
                                                  short* __restrict__ vt) {
  __shared__ short lv[128][72];
  const int h = blockIdx.y, t0 = blockIdx.x * 128;
  const float lamb = *lambp;
  const int tid = threadIdx.x;
  #pragma unroll 4
  for (int it = 0; it < 32; ++it) {
    int e = it * 256 + tid;
    int tl = e >> 6, d = e & 63;
    float v = Cq[(size_t)(t0 + tl) * 3072 + 2048 + h * 64 + d];
    float w = v1[(size_t)(t0 + tl) * 1024 + h * 64 + d];
    lv[tl][d] = f2bs((1.f - lamb) * v + lamb * w);
  }
  __syncthreads();
  #pragma unroll 4
  for (int it = 0; it < 32; ++it) {
    int e = it * 256 + tid;
    int d = e >> 7, tl = e & 127;
    vt[((size_t)h * 64 + d) * T_SEQ + t0 + tl] = lv[tl][d];
  }
}

// ---------------- causal flash attention ----------------
// 4 waves/block; wave owns 16 q-rows; kv tiles of 32; gate fused in epilogue.
__global__ __launch_bounds__(256) void attn(const short* __restrict__ qb,
                                            const short* __restrict__ kb,
                                            const short* __restrict__ vtp,
                                            const float* __restrict__ gate,
                                            short* __restrict__ ob) {
  __shared__ __attribute__((aligned(16))) short p_lds[4][16][40];
  const int h = blockIdx.y;
  const int lane = threadIdx.x & 63, wid = threadIdx.x >> 6;
  const int lr = lane & 15, lg = lane >> 4;
  const int qt0 = blockIdx.x * 64 + wid * 16;
  const short* Q = qb + (size_t)h * T_SEQ * HD;
  const short* Kp = kb + (size_t)h * T_SEQ * HD;
  const short* Vt = vtp + (size_t)h * HD * T_SEQ;
  short (*P)[40] = p_lds[wid];
  bf16x8 aq0 = *(const bf16x8*)&Q[(size_t)(qt0 + lr) * HD + 8 * lg];
  bf16x8 aq1 = *(const bf16x8*)&Q[(size_t)(qt0 + lr) * HD + 32 + 8 * lg];
  f32x4 accO[4] = {};
  float mrow[4] = {-1e30f, -1e30f, -1e30f, -1e30f};
  float lrow[4] = {0.f, 0.f, 0.f, 0.f};
  const int jmax = (qt0 + 15) >> 5;
  for (int j = 0; j <= jmax; ++j) {
    const int kv0 = j * 32;
    f32x4 s0 = {}, s1 = {};
    {
      bf16x8 bk00 = *(const bf16x8*)&Kp[(size_t)(kv0 + lr) * HD + 8 * lg];
      bf16x8 bk01 = *(const bf16x8*)&Kp[(size_t)(kv0 + lr) * HD + 32 + 8 * lg];
      bf16x8 bk10 = *(const bf16x8*)&Kp[(size_t)(kv0 + 16 + lr) * HD + 8 * lg];
      bf16x8 bk11 = *(const bf16x8*)&Kp[(size_t)(kv0 + 16 + lr) * HD + 32 + 8 * lg];
      s0 = __builtin_amdgcn_mfma_f32_16x16x32_bf16(aq0, bk00, s0, 0, 0, 0);
      s0 = __builtin_amdgcn_mfma_f32_16x16x32_bf16(aq1, bk01, s0, 0, 0, 0);
      s1 = __builtin_amdgcn_mfma_f32_16x16x32_bf16(aq0, bk10, s1, 0, 0, 0);
      s1 = __builtin_amdgcn_mfma_f32_16x16x32_bf16(aq1, bk11, s1, 0, 0, 0);
    }
    float alpha[4];
    #pragma unroll
    for (int r = 0; r < 4; ++r) {
      const int trow = qt0 + 4 * lg + r;
      float v0 = (kv0 + lr > trow) ? -1e30f : s0[r] * 0.1f;
      float v1e = (kv0 + 16 + lr > trow) ? -1e30f : s1[r] * 0.1f;
      float mx = fmaxf(v0, v1e);
      mx = fmaxf(mx, __shfl_xor(mx, 1));
      mx = fmaxf(mx, __shfl_xor(mx, 2));
      mx = fmaxf(mx, __shfl_xor(mx, 4));
      mx = fmaxf(mx, __shfl_xor(mx, 8));
      const float mn = fmaxf(mrow[r], mx);
      alpha[r] = __expf(mrow[r] - mn);
      mrow[r] = mn;
      const float p0 = (v0 <= -1e29f) ? 0.f : __expf(v0 - mn);
      const float p1 = (v1e <= -1e29f) ? 0.f : __expf(v1e - mn);
      P[4 * lg + r][lr] = f2bs(p0);
      P[4 * lg + r][16 + lr] = f2bs(p1);
      float ps = p0 + p1;
      ps += __shfl_xor(ps, 1);
      ps += __shfl_xor(ps, 2);
      ps += __shfl_xor(ps, 4);
      ps += __shfl_xor(ps, 8);
      lrow[r] = lrow[r] * alpha[r] + ps;
    }
    #pragma unroll
    for (int nt = 0; nt < 4; ++nt)
      #pragma unroll
      for (int r = 0; r < 4; ++r) accO[nt][r] *= alpha[r];
    // wave-private LDS: cross-lane visibility needs only lgkmcnt(0)
    asm volatile("s_waitcnt lgkmcnt(0)" ::: "memory");
    bf16x8 pa = *(const bf16x8*)&P[lr][8 * lg];
    #pragma unroll
    for (int nt = 0; nt < 4; ++nt) {
      bf16x8 bv = *(const bf16x8*)&Vt[(size_t)(nt * 16 + lr) * T_SEQ + kv0 + 8 * lg];
      accO[nt] = __builtin_amdgcn_mfma_f32_16x16x32_bf16(pa, bv, accO[nt], 0, 0, 0);
    }
  }
  #pragma unroll
  for (int r = 0; r < 4; ++r) {
    const int t = qt0 + 4 * lg + r;
    const float gs = gate[t * 16 + h] / lrow[r];
    #pragma unroll
    for (int nt = 0; nt < 4; ++nt)
      ob[(size_t)t * 1024 + h * 64 + nt * 16 + lr] = f2bs(accO[nt][r] * gs);
  }
}

extern "C" void kernel_launch(void* const* d_in, const int* in_sizes, int n_in,
                              void* d_out, int out_size, void* d_ws, size_t ws_size,
                              hipStream_t stream) {
  const float* x     = (const float*)d_in[0];
  const float* v1    = (const float*)d_in[1];
  const float* Wq    = (const float*)d_in[2];
  const float* Wk    = (const float*)d_in[3];
  const float* Wv    = (const float*)d_in[4];
  const float* Wproj = (const float*)d_in[5];
  const float* lamb  = (const float*)d_in[6];
  const float* Wgate = (const float*)d_in[7];
  float* out = (float*)d_out;

  char* ws = (char*)d_ws;
  short* xb   = (short*)(ws);                    // 4MB   (reused as ob after QKV GEMM)
  short* wqkv = (short*)(ws + ((size_t)4  << 20)); // 6MB
  short* wpj  = (short*)(ws + ((size_t)10 << 20)); // 2MB
  float* Cq   = (float*)(ws + ((size_t)12 << 20)); // 24MB [T][3072]
  short* qb   = (short*)(ws + ((size_t)36 << 20)); // 4MB
  short* kb   = (short*)(ws + ((size_t)40 << 20)); // 4MB
  short* vt   = (short*)(ws + ((size_t)44 << 20)); // 4MB
  float* gate = (float*)(ws + ((size_t)48 << 20)); // 128KB
  short* ob   = xb;                                 // alias: xb dead after QKV GEMM

  cvt_bf16<<<2048, 256, 0, stream>>>(x, xb, 2 * 1024 * 1024);
  cvt_bf16<<<1024, 256, 0, stream>>>(Wq, wqkv, 1024 * 1024);
  cvt_bf16<<<1024, 256, 0, stream>>>(Wk, wqkv + 1024 * 1024, 1024 * 1024);
  cvt_bf16<<<1024, 256, 0, stream>>>(Wv, wqkv + 2 * 1024 * 1024, 1024 * 1024);
  cvt_bf16<<<1024, 256, 0, stream>>>(Wproj, wpj, 1024 * 1024);
  gate_kernel<<<(T_SEQ * NH) / 256, 256, 0, stream>>>(x, Wgate, gate);
  gemm_bt<<<dim3(16, 24), 256, 0, stream>>>(xb, wqkv, Cq, 2048, 3072, 1024);
  qk_norm_rope<<<(T_SEQ * NH) / 4, 256, 0, stream>>>(Cq, qb, kb);
  v_blend_tr<<<dim3(T_SEQ / 128, NH), 256, 0, stream>>>(Cq, v1, lamb, vt);
  attn<<<dim3(T_SEQ / 64, NH), 256, 0, stream>>>(qb, kb, vt, gate, ob);
  gemm_bt<<<dim3(16, 8), 256, 0, stream>>>(ob, wpj, out, 2048, 1024, 1024);
  hipMemcpyAsync(out + (size_t)T_SEQ * 1024, v1,
                 (size_t)T_SEQ * 1024 * sizeof(float),
                 hipMemcpyDeviceToDevice, stream);
}

// Round 2
// 195.186 us; speedup vs baseline: 1.1444x; 1.1444x over previous
//
#include <hip/hip_runtime.h>
#include <hip/hip_bf16.h>

#define T_SEQ 2048
#define NH 16
#define HD 64
// 0.1 (attn scale) * log2(e) folded into q at norm time -> softmax uses exp2
#define SCALE_LOG2E 0.14426950408889634f

typedef __attribute__((ext_vector_type(8))) short bf16x8;
typedef __attribute__((ext_vector_type(4))) short bf16x4;
typedef __attribute__((ext_vector_type(4))) float f32x4;

__device__ __forceinline__ short f2bs(float f) {
  union { float f; unsigned u; } v; v.f = f;
  unsigned r = v.u + 0x7fffu + ((v.u >> 16) & 1u);
  return (short)(r >> 16);
}

__device__ __forceinline__ unsigned cvt_pk_bf16(float lo, float hi) {
  unsigned r;
  asm("v_cvt_pk_bf16_f32 %0, %1, %2" : "=v"(r) : "v"(lo), "v"(hi));
  return r;
}

__device__ __forceinline__ void gload16(const short* g, short* l) {
  __builtin_amdgcn_global_load_lds(
      (const __attribute__((address_space(1))) void*)g,
      (__attribute__((address_space(3))) void*)l, 16, 0, 0);
}

// ---------------- fused f32 -> bf16 convert (x, Wq|Wk|Wv, Wproj) ----------------
__global__ __launch_bounds__(256) void cvt_all(const float* __restrict__ x,
                                               const float* __restrict__ wq,
                                               const float* __restrict__ wk,
                                               const float* __restrict__ wv,
                                               const float* __restrict__ wp,
                                               short* __restrict__ xb,
                                               short* __restrict__ wqkv,
                                               short* __restrict__ wpj) {
  size_t i4 = (size_t)(blockIdx.x * 256 + threadIdx.x) * 4;  // over 6M elements
  const int seg = (int)(i4 >> 20);
  const size_t off = i4 & ((1u << 20) - 1);
  const float* src;
  short* dst;
  if (seg < 2)       { src = x + i4;   dst = xb + i4; }
  else if (seg == 2) { src = wq + off; dst = wqkv + off; }
  else if (seg == 3) { src = wk + off; dst = wqkv + (1u << 20) + off; }
  else if (seg == 4) { src = wv + off; dst = wqkv + (2u << 20) + off; }
  else               { src = wp + off; dst = wpj + off; }
  float4 v = *reinterpret_cast<const float4*>(src);
  bf16x4 o; o[0] = f2bs(v.x); o[1] = f2bs(v.y); o[2] = f2bs(v.z); o[3] = f2bs(v.w);
  *reinterpret_cast<bf16x4*>(dst) = o;
}

// ---------------- gate: sigmoid(x[:, :12] @ Wgate^T) ----------------
__global__ __launch_bounds__(256) void gate_kernel(const float* __restrict__ x,
                                                   const float* __restrict__ Wg,
                                                   float* __restrict__ gate) {
  int id = blockIdx.x * 256 + threadIdx.x;  // t*16 + h
  int t = id >> 4, h = id & 15;
  float acc = 0.f;
  #pragma unroll
  for (int i = 0; i < 12; ++i) acc += x[(size_t)t * 1024 + i] * Wg[h * 12 + i];
  gate[id] = 1.f / (1.f + __expf(-acc));
}

// ---------------- GEMM: C[M][N] = A[M][K] * B[N][K]^T (bf16 in, f32 out) ----------------
// 128x128 tile, BK=32, 4 waves (2x2); global_load_lds width-16 staging (m97 recipe).
__global__ __launch_bounds__(256) void gemm_bt(const short* __restrict__ A,
                                               const short* __restrict__ B,
                                               float* __restrict__ C,
                                               int M, int N, int K) {
  __shared__ __attribute__((aligned(16))) short As[4][128][8];
  __shared__ __attribute__((aligned(16))) short Bs[4][128][8];
  const int tid = threadIdx.x;
  const int lane = tid & 63, wid = tid >> 6;
  const int lr = lane & 15, lg = lane >> 4;
  const int wm = (wid >> 1) * 64, wn = (wid & 1) * 64;
  const int bm = blockIdx.x * 128, bn = blockIdx.y * 128;
  // wave `wid` stages k-slot `wid` (k offset wid*8) for all 128 rows of A and B
  const short* Ap = A + (size_t)(bm + lane) * K + wid * 8;
  const short* Bp = B + (size_t)(bn + lane) * K + wid * 8;
  f32x4 acc[4][4] = {};
  for (int k0 = 0; k0 < K; k0 += 32) {
    __syncthreads();  // previous iteration's fragment reads done
    gload16(Ap + k0, &As[wid][0][0]);
    gload16(Ap + (size_t)64 * K + k0, &As[wid][64][0]);
    gload16(Bp + k0, &Bs[wid][0][0]);
    gload16(Bp + (size_t)64 * K + k0, &Bs[wid][64][0]);
    __syncthreads();  // drains vmcnt -> LDS tiles ready
    bf16x8 af[4], bfr[4];
    #pragma unroll
    for (int m = 0; m < 4; ++m) af[m] = *(const bf16x8*)&As[lg][wm + m * 16 + lr][0];
    #pragma unroll
    for (int n = 0; n < 4; ++n) bfr[n] = *(const bf16x8*)&Bs[lg][wn + n * 16 + lr][0];
    #pragma unroll
    for (int m = 0; m < 4; ++m)
      #pragma unroll
      for (int n = 0; n < 4; ++n)
        acc[m][n] = __builtin_amdgcn_mfma_f32_16x16x32_bf16(af[m], bfr[n], acc[m][n], 0, 0, 0);
  }
  #pragma unroll
  for (int m = 0; m < 4; ++m) {
    const int row = bm + wm + m * 16 + 4 * lg;
    #pragma unroll
    for (int r = 0; r < 4; ++r) {
      float* Cr = C + (size_t)(row + r) * N + bn + wn + lr;
      #pragma unroll
      for (int n = 0; n < 4; ++n) Cr[n * 16] = acc[m][n][r];
    }
  }
}

// ---------------- q/k RMSNorm + RoPE (one wave per (t,h)) ----------------
__global__ __launch_bounds__(256) void qk_norm_rope(const float* __restrict__ Cq,
                                                    short* __restrict__ qb,
                                                    short* __restrict__ kb) {
  int wgid = blockIdx.x * 4 + (threadIdx.x >> 6);
  int lane = threadIdx.x & 63;
  int t = wgid >> 4, h = wgid & 15;
  float qv = Cq[(size_t)t * 3072 + h * 64 + lane];
  float kv = Cq[(size_t)t * 3072 + 1024 + h * 64 + lane];
  float sq = qv * qv, sk = kv * kv;
  #pragma unroll
  for (int o = 1; o < 64; o <<= 1) { sq += __shfl_xor(sq, o); sk += __shfl_xor(sk, o); }
  qv *= rsqrtf(sq * (1.f / 64.f) + 1e-6f);
  kv *= rsqrtf(sk * (1.f / 64.f) + 1e-6f);
  int p = lane & 31;
  // inv_freq = 10000^(-p/32) = exp2(-p * log2(10000)/32)
  float inv_freq = __builtin_exp2f(-0.41524101186092f * (float)p);
  float ang = (float)t * inv_freq;
  float s, c;
  sincosf(ang, &s, &c);
  float qo = __shfl_xor(qv, 32), ko = __shfl_xor(kv, 32);
  float qr = (lane < 32) ? (qv * c + qo * s) : (qv * c - qo * s);
  float kr = (lane < 32) ? (kv * c + ko * s) : (kv * c - ko * s);
  qb[((size_t)h * T_SEQ + t) * 64 + lane] = f2bs(qr * SCALE_LOG2E);
  kb[((size_t)h * T_SEQ + t) * 64 + lane] = f2bs(kr);
}

// ---------------- v blend + transpose to vt[h][hd][kv'] (kv permuted per 32-block) ----
// kv' column c within each 32-block holds actual kv = (c&1)*16 + (c>>1), so that
// attention's P-pack (p_t0, p_t1) lands in adjacent columns. Permutation commutes
// through the PV sum since P columns use the same mapping.
__global__ __launch_bounds__(256) void v_blend_tr(const float* __restrict__ Cq,
                                                  const float* __restrict__ v1,
                                                  const float* __restrict__ lambp,
                                                  short* __restrict__ vt) {
  __shared__ short lv[128][72];
  const int h = blockIdx.y, t0 = blockIdx.x * 128;
  const float lamb = *lambp;
  const int tid = threadIdx.x;
  #pragma unroll 4
  for (int it = 0; it < 32; ++it) {
    int e = it * 256 + tid;
    int tl = e >> 6, d = e & 63;
    float v = Cq[(size_t)(t0 + tl) * 3072 + 2048 + h * 64 + d];
    float w = v1[(size_t)(t0 + tl) * 1024 + h * 64 + d];
    lv[tl][d] = f2bs((1.f - lamb) * v + lamb * w);
  }
  __syncthreads();
  #pragma unroll 4
  for (int it = 0; it < 32; ++it) {
    int e = it * 256 + tid;
    int d = e >> 7, tl = e & 127;
    int src = (tl & 96) + ((tl & 1) << 4) + ((tl >> 1) & 15);  // permuted source row
    vt[((size_t)h * 64 + d) * T_SEQ + t0 + tl] = lv[src][d];
  }
}

// ---------------- causal attention, simplified softmax (no online max) ----------------
// Scores bounded: |q_hat|=|k_hat|=8 -> s in [-6.4,6.4], exp in [1.7e-3, 600]: safe
// in f32/bf16 without max subtraction. q pre-scaled by 0.1*log2e -> p = exp2(s).
__global__ __launch_bounds__(256) void attn(const short* __restrict__ qb,
                                            const short* __restrict__ kb,
                                            const short* __restrict__ vtp,
                                            const float* __restrict__ gate,
                                            short* __restrict__ ob) {
  __shared__ __attribute__((aligned(16))) short p_lds[4][16][72];
  const int id = blockIdx.x;
  const int head = id & 15;
  const int qg = 31 - (id >> 4);  // heavy-first dispatch order (LPT balance)
  const int lane = threadIdx.x & 63, wid = threadIdx.x >> 6;
  const int lr = lane & 15, lg = lane >> 4;
  const int qt0 = qg * 64 + wid * 16;
  const short* Q = qb + (size_t)head * (T_SEQ * HD);
  const short* Kp = kb + (size_t)head * (T_SEQ * HD);
  const short* Vt = vtp + (size_t)head * (HD * T_SEQ);
  short (*P)[72] = p_lds[wid];

  bf16x8 aq0 = *(const bf16x8*)&Q[(size_t)(qt0 + lr) * HD + 8 * lg];
  bf16x8 aq1 = *(const bf16x8*)&Q[(size_t)(qt0 + lr) * HD + 32 + 8 * lg];
  f32x4 accO[4] = {};
  float lsum[4] = {0.f, 0.f, 0.f, 0.f};
  const int ntile = (qt0 + 79) >> 6;                          // KVBLK = 64
  const int nfull = (qt0 >= 63) ? (((qt0 - 63) >> 6) + 1) : 0;  // j < nfull: unmasked
  for (int j = 0; j < ntile; ++j) {
    const int kv0 = j * 64;
    // issue V loads early: latency hides under QK^T + softmax
    bf16x8 bv0[4], bv1[4];
    #pragma unroll
    for (int nt = 0; nt < 4; ++nt) {
      const short* Vd = &Vt[(size_t)(nt * 16 + lr) * T_SEQ + kv0];
      bv0[nt] = *(const bf16x8*)&Vd[8 * lg];
      bv1[nt] = *(const bf16x8*)&Vd[32 + 8 * lg];
    }
    f32x4 st[4];
    #pragma unroll
    for (int t = 0; t < 4; ++t) {
      const short* Kt = &Kp[(size_t)(kv0 + 16 * t + lr) * HD];
      bf16x8 k0 = *(const bf16x8*)&Kt[8 * lg];
      bf16x8 k1 = *(const bf16x8*)&Kt[32 + 8 * lg];
      f32x4 s = {};
      s = __builtin_amdgcn_mfma_f32_16x16x32_bf16(aq0, k0, s, 0, 0, 0);
      s = __builtin_amdgcn_mfma_f32_16x16x32_bf16(aq1, k1, s, 0, 0, 0);
      st[t] = s;
    }
    if (j >= nfull) {  // boundary tile: mask (wave-uniform branch)
      #pragma unroll
      for (int t = 0; t < 4; ++t)
        #pragma unroll
        for (int r = 0; r < 4; ++r)
          st[t][r] = (kv0 + 16 * t + lr > qt0 + 4 * lg + r) ? -1e30f : st[t][r];
    }
    #pragma unroll
    for (int r = 0; r < 4; ++r) {
      float p0 = __builtin_exp2f(st[0][r]);
      float p1 = __builtin_exp2f(st[1][r]);
      float p2 = __builtin_exp2f(st[2][r]);
      float p3 = __builtin_exp2f(st[3][r]);
      lsum[r] += (p0 + p1) + (p2 + p3);
      // packed pairs land at permuted columns c=2*lr (kv=lr) and c=2*lr+1 (kv=16+lr)
      *(unsigned*)&P[4 * lg + r][2 * lr] = cvt_pk_bf16(p0, p1);
      *(unsigned*)&P[4 * lg + r][32 + 2 * lr] = cvt_pk_bf16(p2, p3);
    }
    asm volatile("s_waitcnt lgkmcnt(0)" ::: "memory");  // wave-private LDS visibility
    bf16x8 pa0 = *(const bf16x8*)&P[lr][8 * lg];
    bf16x8 pa1 = *(const bf16x8*)&P[lr][32 + 8 * lg];
    #pragma unroll
    for (int nt = 0; nt < 4; ++nt) {
      accO[nt] = __builtin_amdgcn_mfma_f32_16x16x32_bf16(pa0, bv0[nt], accO[nt], 0, 0, 0);
      accO[nt] = __builtin_amdgcn_mfma_f32_16x16x32_bf16(pa1, bv1[nt], accO[nt], 0, 0, 0);
    }
  }
  #pragma unroll
  for (int r = 0; r < 4; ++r) {
    float s = lsum[r];
    s += __shfl_xor(s, 1);
    s += __shfl_xor(s, 2);
    s += __shfl_xor(s, 4);
    s += __shfl_xor(s, 8);
    const int t = qt0 + 4 * lg + r;
    const float gs = gate[t * 16 + head] / s;
    #pragma unroll
    for (int nt = 0; nt < 4; ++nt)
      ob[(size_t)t * 1024 + head * 64 + nt * 16 + lr] = f2bs(accO[nt][r] * gs);
  }
}

extern "C" void kernel_launch(void* const* d_in, const int* in_sizes, int n_in,
                              void* d_out, int out_size, void* d_ws, size_t ws_size,
                              hipStream_t stream) {
  const float* x     = (const float*)d_in[0];
  const float* v1    = (const float*)d_in[1];
  const float* Wq    = (const float*)d_in[2];
  const float* Wk    = (const float*)d_in[3];
  const float* Wv    = (const float*)d_in[4];
  const float* Wproj = (const float*)d_in[5];
  const float* lamb  = (const float*)d_in[6];
  const float* Wgate = (const float*)d_in[7];
  float* out = (float*)d_out;

  char* ws = (char*)d_ws;
  short* xb   = (short*)(ws);                      // 4MB (reused as ob after QKV GEMM)
  short* wqkv = (short*)(ws + ((size_t)4  << 20)); // 6MB
  short* wpj  = (short*)(ws + ((size_t)10 << 20)); // 2MB
  float* Cq   = (float*)(ws + ((size_t)12 << 20)); // 24MB [T][3072]
  short* qb   = (short*)(ws + ((size_t)36 << 20)); // 4MB
  short* kb   = (short*)(ws + ((size_t)40 << 20)); // 4MB
  short* vt   = (short*)(ws + ((size_t)44 << 20)); // 4MB
  float* gate = (float*)(ws + ((size_t)48 << 20)); // 128KB
  short* ob   = xb;

  cvt_all<<<6144, 256, 0, stream>>>(x, Wq, Wk, Wv, Wproj, xb, wqkv, wpj);
  gate_kernel<<<(T_SEQ * NH) / 256, 256, 0, stream>>>(x, Wgate, gate);
  gemm_bt<<<dim3(16, 24), 256, 0, stream>>>(xb, wqkv, Cq, 2048, 3072, 1024);
  qk_norm_rope<<<(T_SEQ * NH) / 4, 256, 0, stream>>>(Cq, qb, kb);
  v_blend_tr<<<dim3(T_SEQ / 128, NH), 256, 0, stream>>>(Cq, v1, lamb, vt);
  attn<<<512, 256, 0, stream>>>(qb, kb, vt, gate, ob);
  gemm_bt<<<dim3(16, 8), 256, 0, stream>>>(ob, wpj, out, 2048, 1024, 1024);
  hipMemcpyAsync(out + (size_t)T_SEQ * 1024, v1,
                 (size_t)T_SEQ * 1024 * sizeof(float),
                 hipMemcpyDeviceToDevice, stream);
}

// Round 4
// 135.051 us; speedup vs baseline: 1.6540x; 1.4453x over previous
//
#include <hip/hip_runtime.h>
#include <hip/hip_bf16.h>

#define T_SEQ 2048
#define NH 16
#define HD 64
// 0.1 (attn scale) * log2(e) folded into q at norm time -> softmax uses exp2
#define SCALE_LOG2E 0.14426950408889634f

typedef __attribute__((ext_vector_type(8))) short bf16x8;
typedef __attribute__((ext_vector_type(4))) short bf16x4;
typedef __attribute__((ext_vector_type(4))) float f32x4;

__device__ __forceinline__ short f2bs(float f) {
  union { float f; unsigned u; } v; v.f = f;
  unsigned r = v.u + 0x7fffu + ((v.u >> 16) & 1u);
  return (short)(r >> 16);
}

__device__ __forceinline__ unsigned cvt_pk_bf16(float lo, float hi) {
  unsigned r;
  asm("v_cvt_pk_bf16_f32 %0, %1, %2" : "=v"(r) : "v"(lo), "v"(hi));
  return r;
}

__device__ __forceinline__ void gload16(const short* g, short* l) {
  __builtin_amdgcn_global_load_lds(
      (const __attribute__((address_space(1))) void*)g,
      (__attribute__((address_space(3))) void*)l, 16, 0, 0);
}

// ---------------- fused f32 -> bf16 convert (x, Wq|Wk|Wv, Wproj) ----------------
__global__ __launch_bounds__(256) void cvt_all(const float* __restrict__ x,
                                               const float* __restrict__ wq,
                                               const float* __restrict__ wk,
                                               const float* __restrict__ wv,
                                               const float* __restrict__ wp,
                                               short* __restrict__ xb,
                                               short* __restrict__ wqkv,
                                               short* __restrict__ wpj) {
  size_t i4 = (size_t)(blockIdx.x * 256 + threadIdx.x) * 4;  // over 6M elements
  const int seg = (int)(i4 >> 20);
  const size_t off = i4 & ((1u << 20) - 1);
  const float* src;
  short* dst;
  if (seg < 2)       { src = x + i4;   dst = xb + i4; }
  else if (seg == 2) { src = wq + off; dst = wqkv + off; }
  else if (seg == 3) { src = wk + off; dst = wqkv + (1u << 20) + off; }
  else if (seg == 4) { src = wv + off; dst = wqkv + (2u << 20) + off; }
  else               { src = wp + off; dst = wpj + off; }
  float4 v = *reinterpret_cast<const float4*>(src);
  bf16x4 o; o[0] = f2bs(v.x); o[1] = f2bs(v.y); o[2] = f2bs(v.z); o[3] = f2bs(v.w);
  *reinterpret_cast<bf16x4*>(dst) = o;
}

// ---------------- gate: sigmoid(x[:, :12] @ Wgate^T) ----------------
__global__ __launch_bounds__(256) void gate_kernel(const float* __restrict__ x,
                                                   const float* __restrict__ Wg,
                                                   float* __restrict__ gate) {
  int id = blockIdx.x * 256 + threadIdx.x;  // t*16 + h
  int t = id >> 4, h = id & 15;
  float acc = 0.f;
  #pragma unroll
  for (int i = 0; i < 12; ++i) acc += x[(size_t)t * 1024 + i] * Wg[h * 12 + i];
  gate[id] = 1.f / (1.f + __expf(-acc));
}

// ---------------- GEMM: C[M][N] = A[M][K] * B[N][K]^T (bf16 in, f32 out) ----------------
// 128x128 tile, BK=32, 4 waves (2x2); global_load_lds width-16 staging (m97 recipe).
__global__ __launch_bounds__(256) void gemm_bt(const short* __restrict__ A,
                                               const short* __restrict__ B,
                                               float* __restrict__ C,
                                               int M, int N, int K) {
  __shared__ __attribute__((aligned(16))) short As[4][128][8];
  __shared__ __attribute__((aligned(16))) short Bs[4][128][8];
  const int tid = threadIdx.x;
  const int lane = tid & 63, wid = tid >> 6;
  const int lr = lane & 15, lg = lane >> 4;
  const int wm = (wid >> 1) * 64, wn = (wid & 1) * 64;
  const int bm = blockIdx.x * 128, bn = blockIdx.y * 128;
  // wave `wid` stages k-slot `wid` (k offset wid*8) for all 128 rows of A and B
  const short* Ap = A + (size_t)(bm + lane) * K + wid * 8;
  const short* Bp = B + (size_t)(bn + lane) * K + wid * 8;
  f32x4 acc[4][4] = {};
  for (int k0 = 0; k0 < K; k0 += 32) {
    __syncthreads();  // previous iteration's fragment reads done
    gload16(Ap + k0, &As[wid][0][0]);
    gload16(Ap + (size_t)64 * K + k0, &As[wid][64][0]);
    gload16(Bp + k0, &Bs[wid][0][0]);
    gload16(Bp + (size_t)64 * K + k0, &Bs[wid][64][0]);
    __syncthreads();  // drains vmcnt -> LDS tiles ready
    bf16x8 af[4], bfr[4];
    #pragma unroll
    for (int m = 0; m < 4; ++m) af[m] = *(const bf16x8*)&As[lg][wm + m * 16 + lr][0];
    #pragma unroll
    for (int n = 0; n < 4; ++n) bfr[n] = *(const bf16x8*)&Bs[lg][wn + n * 16 + lr][0];
    #pragma unroll
    for (int m = 0; m < 4; ++m)
      #pragma unroll
      for (int n = 0; n < 4; ++n)
        acc[m][n] = __builtin_amdgcn_mfma_f32_16x16x32_bf16(af[m], bfr[n], acc[m][n], 0, 0, 0);
  }
  #pragma unroll
  for (int m = 0; m < 4; ++m) {
    const int row = bm + wm + m * 16 + 4 * lg;
    #pragma unroll
    for (int r = 0; r < 4; ++r) {
      float* Cr = C + (size_t)(row + r) * N + bn + wn + lr;
      #pragma unroll
      for (int n = 0; n < 4; ++n) Cr[n * 16] = acc[m][n][r];
    }
  }
}

// ---------------- q/k RMSNorm + RoPE (one wave per (t,h)) ----------------
__global__ __launch_bounds__(256) void qk_norm_rope(const float* __restrict__ Cq,
                                                    short* __restrict__ qb,
                                                    short* __restrict__ kb) {
  int wgid = blockIdx.x * 4 + (threadIdx.x >> 6);
  int lane = threadIdx.x & 63;
  int t = wgid >> 4, h = wgid & 15;
  float qv = Cq[(size_t)t * 3072 + h * 64 + lane];
  float kv = Cq[(size_t)t * 3072 + 1024 + h * 64 + lane];
  float sq = qv * qv, sk = kv * kv;
  #pragma unroll
  for (int o = 1; o < 64; o <<= 1) { sq += __shfl_xor(sq, o); sk += __shfl_xor(sk, o); }
  qv *= rsqrtf(sq * (1.f / 64.f) + 1e-6f);
  kv *= rsqrtf(sk * (1.f / 64.f) + 1e-6f);
  int p = lane & 31;
  // inv_freq = 10000^(-p/32) = exp2(-p * log2(10000)/32)
  float inv_freq = __builtin_exp2f(-0.41524101186092f * (float)p);
  float ang = (float)t * inv_freq;
  float s, c;
  sincosf(ang, &s, &c);
  float qo = __shfl_xor(qv, 32), ko = __shfl_xor(kv, 32);
  float qr = (lane < 32) ? (qv * c + qo * s) : (qv * c - qo * s);
  float kr = (lane < 32) ? (kv * c + ko * s) : (kv * c - ko * s);
  qb[((size_t)h * T_SEQ + t) * 64 + lane] = f2bs(qr * SCALE_LOG2E);
  kb[((size_t)h * T_SEQ + t) * 64 + lane] = f2bs(kr);
}

// ---------------- v blend + transpose to vt[h][hd][kv'] (kv permuted per 32-block) ----
// kv' column c within each 32-block holds actual kv = (c&1)*16 + (c>>1), so that
// attention's P-pack (p_t0, p_t1) lands in adjacent columns. Permutation commutes
// through the PV sum since P columns use the same mapping.
__global__ __launch_bounds__(256) void v_blend_tr(const float* __restrict__ Cq,
                                                  const float* __restrict__ v1,
                                                  const float* __restrict__ lambp,
                                                  short* __restrict__ vt) {
  __shared__ short lv[128][72];
  const int h = blockIdx.y, t0 = blockIdx.x * 128;
  const float lamb = *lambp;
  const int tid = threadIdx.x;
  #pragma unroll 4
  for (int it = 0; it < 32; ++it) {
    int e = it * 256 + tid;
    int tl = e >> 6, d = e & 63;
    float v = Cq[(size_t)(t0 + tl) * 3072 + 2048 + h * 64 + d];
    float w = v1[(size_t)(t0 + tl) * 1024 + h * 64 + d];
    lv[tl][d] = f2bs((1.f - lamb) * v + lamb * w);
  }
  __syncthreads();
  #pragma unroll 4
  for (int it = 0; it < 32; ++it) {
    int e = it * 256 + tid;
    int d = e >> 7, tl = e & 127;
    int src = (tl & 96) + ((tl & 1) << 4) + ((tl >> 1) & 15);  // permuted source row
    vt[((size_t)h * 64 + d) * T_SEQ + t0 + tl] = lv[src][d];
  }
}

// ---------------- causal attention, split-KV, LDS-staged K/V (double-buffered) -------
// No online max needed (scores bounded by RMS norm): partials over kv strips combine
// by plain addition of accO and lsum -> split-KV grid (head, qgroup64, strip512).
// Partials stored COMPACTLY at slot = head*80 + b (b = linear job id 0..79): exactly
// 1280 slots * 4160 floats = 20.3MB, fits the 24MB Cq region (round-3 bug: sparse
// (head,qg,strip) indexing needed 34MB and clobbered qb/kb -> NaN).
__global__ __launch_bounds__(256) void attn(const short* __restrict__ qb,
                                            const short* __restrict__ kb,
                                            const short* __restrict__ vtp,
                                            float* __restrict__ part) {
  __shared__ __attribute__((aligned(16))) short Ks[2][4096];
  __shared__ __attribute__((aligned(16))) short Vs[2][4096];
  __shared__ __attribute__((aligned(16))) short p_lds[4][16][72];
  const int head = blockIdx.x & 15;
  const int b = blockIdx.x >> 4;  // 0..79
  int strip, qg;  // heavy-first (qg descending) within each strip class
  if (b < 32)      { strip = 0; qg = 31 - b; }
  else if (b < 56) { strip = 1; qg = 63 - b; }   // qg 31..8
  else if (b < 72) { strip = 2; qg = 87 - b; }   // qg 31..16
  else             { strip = 3; qg = 103 - b; }  // qg 31..24
  const int nt = min(8, qg + 1 - strip * 8);
  const int lane = threadIdx.x & 63, wid = threadIdx.x >> 6;
  const int lr = lane & 15, lg = lane >> 4;
  const int qt0 = qg * 64 + wid * 16;
  const short* Q = qb + (size_t)head * (T_SEQ * HD);
  const short* Kp = kb + (size_t)head * (T_SEQ * HD);
  const short* Vt = vtp + (size_t)head * (HD * T_SEQ);
  short (*P)[72] = p_lds[wid];

  bf16x8 aq0 = *(const bf16x8*)&Q[(size_t)(qt0 + lr) * HD + 8 * lg];
  bf16x8 aq1 = *(const bf16x8*)&Q[(size_t)(qt0 + lr) * HD + 32 + 8 * lg];
  f32x4 accO[4] = {};
  float lsum[4] = {0.f, 0.f, 0.f, 0.f};

  auto stage = [&](int buf, int jg) {
    const int kv0 = jg * 64;
    #pragma unroll
    for (int i = 0; i < 2; ++i) {
      int s = i * 256 + wid * 64 + lane;       // chunk id 0..511 (16B chunks)
      int row = s >> 3;                        // tile row 0..63
      int cG = (s & 7) ^ (row & 7);            // inverse-swizzled source chunk
      gload16(Kp + (size_t)(kv0 + row) * HD + cG * 8,
              &Ks[buf][(size_t)(i * 256 + wid * 64) * 8]);
      gload16(Vt + (size_t)row * T_SEQ + kv0 + cG * 8,
              &Vs[buf][(size_t)(i * 256 + wid * 64) * 8]);
    }
  };
  stage(0, strip * 8);
  for (int j = 0; j < nt; ++j) {
    const int jg = strip * 8 + j;
    __syncthreads();                            // drains vmcnt: buf[j&1] ready
    if (j + 1 < nt) stage((j + 1) & 1, jg + 1); // prefetch stays in flight
    const short* Kb = Ks[j & 1];
    const short* Vb = Vs[j & 1];
    f32x4 st[4];
    #pragma unroll
    for (int t = 0; t < 4; ++t) {
      int row = 16 * t + lr;
      int c0 = lg ^ (row & 7);
      bf16x8 k0 = *(const bf16x8*)&Kb[row * 64 + c0 * 8];
      bf16x8 k1 = *(const bf16x8*)&Kb[row * 64 + (c0 ^ 4) * 8];
      f32x4 s = {};
      s = __builtin_amdgcn_mfma_f32_16x16x32_bf16(aq0, k0, s, 0, 0, 0);
      s = __builtin_amdgcn_mfma_f32_16x16x32_bf16(aq1, k1, s, 0, 0, 0);
      st[t] = s;
    }
    if (jg == qg) {  // diagonal tile: causal mask (block-uniform branch)
      #pragma unroll
      for (int t = 0; t < 4; ++t)
        #pragma unroll
        for (int r = 0; r < 4; ++r)
          st[t][r] = (16 * t + lr > wid * 16 + 4 * lg + r) ? -1e30f : st[t][r];
    }
    #pragma unroll
    for (int r = 0; r < 4; ++r) {
      float p0 = __builtin_exp2f(st[0][r]);
      float p1 = __builtin_exp2f(st[1][r]);
      float p2 = __builtin_exp2f(st[2][r]);
      float p3 = __builtin_exp2f(st[3][r]);
      lsum[r] += (p0 + p1) + (p2 + p3);
      *(unsigned*)&P[4 * lg + r][2 * lr] = cvt_pk_bf16(p0, p1);
      *(unsigned*)&P[4 * lg + r][32 + 2 * lr] = cvt_pk_bf16(p2, p3);
    }
    asm volatile("s_waitcnt lgkmcnt(0)" ::: "memory");  // wave-private P roundtrip
    __builtin_amdgcn_sched_barrier(0);
    bf16x8 pa0 = *(const bf16x8*)&P[lr][8 * lg];
    bf16x8 pa1 = *(const bf16x8*)&P[lr][32 + 8 * lg];
    #pragma unroll
    for (int nv = 0; nv < 4; ++nv) {
      int row0 = nv * 16 + lr;
      int c0 = lg ^ (row0 & 7);
      bf16x8 v0 = *(const bf16x8*)&Vb[row0 * 64 + c0 * 8];
      bf16x8 v1 = *(const bf16x8*)&Vb[row0 * 64 + (c0 ^ 4) * 8];
      accO[nv] = __builtin_amdgcn_mfma_f32_16x16x32_bf16(pa0, v0, accO[nv], 0, 0, 0);
      accO[nv] = __builtin_amdgcn_mfma_f32_16x16x32_bf16(pa1, v1, accO[nv], 0, 0, 0);
    }
  }
  // write partials: 64x64 O block + 64 lsum, compact slot = head*80 + b
  float* pO = part + (size_t)(head * 80 + b) * 4160;
  float* pL = pO + 4096;
  #pragma unroll
  for (int r = 0; r < 4; ++r) {
    float sres = lsum[r];
    sres += __shfl_xor(sres, 1);
    sres += __shfl_xor(sres, 2);
    sres += __shfl_xor(sres, 4);
    sres += __shfl_xor(sres, 8);
    int row = wid * 16 + 4 * lg + r;
    #pragma unroll
    for (int nv = 0; nv < 4; ++nv)
      pO[row * 64 + nv * 16 + lr] = accO[nv][r];
    if (lr == 0) pL[row] = sres;
  }
}

// ---------------- combine split-KV partials, apply gate, write bf16 ----------------
__global__ __launch_bounds__(256) void attn_reduce(const float* __restrict__ part,
                                                   const float* __restrict__ gate,
                                                   short* __restrict__ ob) {
  const int head = blockIdx.x & 15;
  const int qg = blockIdx.x >> 4;
  const int ns = (qg >> 3) + 1;
  const int tid = threadIdx.x;
  const int row = tid >> 2, q4 = tid & 3;
  const int sbase[4] = {0, 32, 56, 72};  // strip -> b base (b = sbase[s] + 31 - qg)
  f32x4 o[4] = {};
  float l = 0.f;
  for (int s = 0; s < ns; ++s) {
    const float* pb = part + (size_t)(head * 80 + sbase[s] + 31 - qg) * 4160;
    #pragma unroll
    for (int c = 0; c < 4; ++c)
      o[c] += *(const f32x4*)&pb[row * 64 + q4 * 16 + c * 4];
    l += pb[4096 + row];
  }
  const int t = qg * 64 + row;
  const float gs = gate[t * 16 + head] / l;
  short* op = ob + (size_t)t * 1024 + head * 64 + q4 * 16;
  #pragma unroll
  for (int c = 0; c < 4; ++c) {
    bf16x4 w;
    w[0] = f2bs(o[c][0] * gs); w[1] = f2bs(o[c][1] * gs);
    w[2] = f2bs(o[c][2] * gs); w[3] = f2bs(o[c][3] * gs);
    *(bf16x4*)&op[c * 4] = w;
  }
}

extern "C" void kernel_launch(void* const* d_in, const int* in_sizes, int n_in,
                              void* d_out, int out_size, void* d_ws, size_t ws_size,
                              hipStream_t stream) {
  const float* x     = (const float*)d_in[0];
  const float* v1    = (const float*)d_in[1];
  const float* Wq    = (const float*)d_in[2];
  const float* Wk    = (const float*)d_in[3];
  const float* Wv    = (const float*)d_in[4];
  const float* Wproj = (const float*)d_in[5];
  const float* lamb  = (const float*)d_in[6];
  const float* Wgate = (const float*)d_in[7];
  float* out = (float*)d_out;

  char* ws = (char*)d_ws;
  short* xb   = (short*)(ws);                      // 4MB (reused as ob after QKV GEMM)
  short* wqkv = (short*)(ws + ((size_t)4  << 20)); // 6MB
  short* wpj  = (short*)(ws + ((size_t)10 << 20)); // 2MB
  float* Cq   = (float*)(ws + ((size_t)12 << 20)); // 24MB [T][3072]; reused as part buf
  short* qb   = (short*)(ws + ((size_t)36 << 20)); // 4MB
  short* kb   = (short*)(ws + ((size_t)40 << 20)); // 4MB
  short* vt   = (short*)(ws + ((size_t)44 << 20)); // 4MB
  float* gate = (float*)(ws + ((size_t)48 << 20)); // 128KB
  short* ob   = xb;
  float* part = Cq;  // compact: 1280 slots * 4160 floats = 20.3MB < 24MB

  cvt_all<<<6144, 256, 0, stream>>>(x, Wq, Wk, Wv, Wproj, xb, wqkv, wpj);
  gate_kernel<<<(T_SEQ * NH) / 256, 256, 0, stream>>>(x, Wgate, gate);
  gemm_bt<<<dim3(16, 24), 256, 0, stream>>>(xb, wqkv, Cq, 2048, 3072, 1024);
  qk_norm_rope<<<(T_SEQ * NH) / 4, 256, 0, stream>>>(Cq, qb, kb);
  v_blend_tr<<<dim3(T_SEQ / 128, NH), 256, 0, stream>>>(Cq, v1, lamb, vt);
  attn<<<1280, 256, 0, stream>>>(qb, kb, vt, part);
  attn_reduce<<<512, 256, 0, stream>>>(part, gate, ob);
  gemm_bt<<<dim3(16, 8), 256, 0, stream>>>(ob, wpj, out, 2048, 1024, 1024);
  hipMemcpyAsync(out + (size_t)T_SEQ * 1024, v1,
                 (size_t)T_SEQ * 1024 * sizeof(float),
                 hipMemcpyDeviceToDevice, stream);
}

// Round 5
// 116.504 us; speedup vs baseline: 1.9173x; 1.1592x over previous
//
#include <hip/hip_runtime.h>
#include <hip/hip_bf16.h>

#define T_SEQ 2048
#define NH 16
#define HD 64
// 0.1 (attn scale) * log2(e) folded into q at norm time -> softmax uses exp2
#define SCALE_LOG2E 0.14426950408889634f

typedef __attribute__((ext_vector_type(8))) short bf16x8;
typedef __attribute__((ext_vector_type(4))) short bf16x4;
typedef __attribute__((ext_vector_type(4))) float f32x4;

__device__ __forceinline__ short f2bs(float f) {
  union { float f; unsigned u; } v; v.f = f;
  unsigned r = v.u + 0x7fffu + ((v.u >> 16) & 1u);
  return (short)(r >> 16);
}

__device__ __forceinline__ unsigned cvt_pk_bf16(float lo, float hi) {
  unsigned r;
  asm("v_cvt_pk_bf16_f32 %0, %1, %2" : "=v"(r) : "v"(lo), "v"(hi));
  return r;
}

__device__ __forceinline__ void gload16(const short* g, short* l) {
  __builtin_amdgcn_global_load_lds(
      (const __attribute__((address_space(1))) void*)g,
      (__attribute__((address_space(3))) void*)l, 16, 0, 0);
}

// ---------------- fused f32 -> bf16 convert (x, Wq|Wk|Wv, Wproj) ----------------
__global__ __launch_bounds__(256) void cvt_all(const float* __restrict__ x,
                                               const float* __restrict__ wq,
                                               const float* __restrict__ wk,
                                               const float* __restrict__ wv,
                                               const float* __restrict__ wp,
                                               short* __restrict__ xb,
                                               short* __restrict__ wqkv,
                                               short* __restrict__ wpj) {
  size_t i4 = (size_t)(blockIdx.x * 256 + threadIdx.x) * 4;  // over 6M elements
  const int seg = (int)(i4 >> 20);
  const size_t off = i4 & ((1u << 20) - 1);
  const float* src;
  short* dst;
  if (seg < 2)       { src = x + i4;   dst = xb + i4; }
  else if (seg == 2) { src = wq + off; dst = wqkv + off; }
  else if (seg == 3) { src = wk + off; dst = wqkv + (1u << 20) + off; }
  else if (seg == 4) { src = wv + off; dst = wqkv + (2u << 20) + off; }
  else               { src = wp + off; dst = wpj + off; }
  float4 v = *reinterpret_cast<const float4*>(src);
  bf16x4 o; o[0] = f2bs(v.x); o[1] = f2bs(v.y); o[2] = f2bs(v.z); o[3] = f2bs(v.w);
  *reinterpret_cast<bf16x4*>(dst) = o;
}

// -------- gate: sigmoid(x[:, :12] @ Wgate^T); also fills rope table (cos,sin) --------
__global__ __launch_bounds__(256) void gate_rope(const float* __restrict__ x,
                                                 const float* __restrict__ Wg,
                                                 float* __restrict__ gate,
                                                 float2* __restrict__ rope) {
  int id = blockIdx.x * 256 + threadIdx.x;  // t*16 + h, 32768 total
  int t = id >> 4, h = id & 15;
  float acc = 0.f;
  #pragma unroll
  for (int i = 0; i < 12; ++i) acc += x[(size_t)t * 1024 + i] * Wg[h * 12 + i];
  gate[id] = 1.f / (1.f + __expf(-acc));
  // rope[t][p]: 65536 entries, 2 per thread
  #pragma unroll
  for (int j = 0; j < 2; ++j) {
    int e = id * 2 + j;
    int tt = e >> 5, p = e & 31;
    float invf = __builtin_exp2f(-0.41524101186092f * (float)p);
    float s, c;
    sincosf((float)tt * invf, &s, &c);
    rope[e] = make_float2(c, s);
  }
}

// ---------------- GEMM: C[M][N] = A[M][K] * B[N][K]^T (bf16 in) ----------------
// BM=64 x BN tile, BK=32, 4 waves (2x2), wave = 32 x BN/2; global_load_lds w16 staging.
// QKV=true: fused epilogue. bn<2048 -> RMSNorm+RoPE -> bf16 qb/kb [h][t][64];
//           bn>=2048 -> plain f32 Cv (cols bn-2048). QKV=false: plain f32 C.
template <int BN, bool QKV>
__global__ __launch_bounds__(256) void gemm64(const short* __restrict__ A,
                                              const short* __restrict__ B,
                                              float* __restrict__ C,
                                              short* __restrict__ qb,
                                              short* __restrict__ kb,
                                              const float2* __restrict__ rope,
                                              int N, int K) {
  constexpr int NB = BN / 32;  // fragments per wave in N
  __shared__ __attribute__((aligned(16))) short As[4][64][8];
  __shared__ __attribute__((aligned(16))) short Bs[4][BN][8];
  const int tid = threadIdx.x;
  const int lane = tid & 63, wid = tid >> 6;
  const int lr = lane & 15, lg = lane >> 4;
  const int wm = (wid >> 1) * 32, wn = (wid & 1) * (BN / 2);
  const int bm = blockIdx.x * 64, bn = blockIdx.y * BN;
  // wave `wid` stages k-slot `wid` (k offset wid*8)
  const short* Ap = A + (size_t)(bm + lane) * K + wid * 8;
  const short* Bp = B + (size_t)(bn + lane) * K + wid * 8;
  f32x4 acc[2][NB] = {};
  for (int k0 = 0; k0 < K; k0 += 32) {
    __syncthreads();  // previous iteration's fragment reads done
    gload16(Ap + k0, &As[wid][0][0]);
    #pragma unroll
    for (int g = 0; g < BN / 64; ++g)
      gload16(Bp + (size_t)(64 * g) * K + k0, &Bs[wid][64 * g][0]);
    __syncthreads();  // drains vmcnt -> LDS tiles ready
    bf16x8 af[2], bfr[NB];
    #pragma unroll
    for (int m = 0; m < 2; ++m) af[m] = *(const bf16x8*)&As[lg][wm + m * 16 + lr][0];
    #pragma unroll
    for (int n = 0; n < NB; ++n) bfr[n] = *(const bf16x8*)&Bs[lg][wn + n * 16 + lr][0];
    #pragma unroll
    for (int m = 0; m < 2; ++m)
      #pragma unroll
      for (int n = 0; n < NB; ++n)
        acc[m][n] = __builtin_amdgcn_mfma_f32_16x16x32_bf16(af[m], bfr[n], acc[m][n], 0, 0, 0);
  }
  if constexpr (QKV) {
    if (bn < 2048) {  // q or k head: wave cols = exactly one head
      const bool isq = (bn < 1024);
      short* dst = isq ? qb : kb;
      const int h = ((bn + wn) & 1023) >> 6;
      #pragma unroll
      for (int m = 0; m < 2; ++m)
        #pragma unroll
        for (int r = 0; r < 4; ++r) {
          const int t = bm + wm + m * 16 + 4 * lg + r;
          float ss = acc[m][0][r] * acc[m][0][r] + acc[m][1][r] * acc[m][1][r]
                   + acc[m][2][r] * acc[m][2][r] + acc[m][3][r] * acc[m][3][r];
          ss += __shfl_xor(ss, 1);
          ss += __shfl_xor(ss, 2);
          ss += __shfl_xor(ss, 4);
          ss += __shfl_xor(ss, 8);
          const float rms = rsqrtf(ss * (1.f / 64.f) + 1e-6f);
          short* row = dst + ((size_t)h * T_SEQ + t) * 64;
          #pragma unroll
          for (int n2 = 0; n2 < 2; ++n2) {  // rope pair (d, d+32) = (n2, n2+2)
            float x1 = acc[m][n2][r] * rms, x2 = acc[m][n2 + 2][r] * rms;
            float2 cs = rope[t * 32 + n2 * 16 + lr];
            float y1 = x1 * cs.x + x2 * cs.y;
            float y2 = x2 * cs.x - x1 * cs.y;
            if (isq) { y1 *= SCALE_LOG2E; y2 *= SCALE_LOG2E; }
            row[n2 * 16 + lr] = f2bs(y1);
            row[32 + n2 * 16 + lr] = f2bs(y2);
          }
        }
    } else {  // v region -> plain f32 Cv [t][1024]
      #pragma unroll
      for (int m = 0; m < 2; ++m)
        #pragma unroll
        for (int r = 0; r < 4; ++r) {
          const int t = bm + wm + m * 16 + 4 * lg + r;
          float* Cr = C + (size_t)t * 1024 + (bn - 2048) + wn + lr;
          #pragma unroll
          for (int n = 0; n < NB; ++n) Cr[n * 16] = acc[m][n][r];
        }
    }
  } else {
    #pragma unroll
    for (int m = 0; m < 2; ++m)
      #pragma unroll
      for (int r = 0; r < 4; ++r) {
        const int t = bm + wm + m * 16 + 4 * lg + r;
        float* Cr = C + (size_t)t * N + bn + wn + lr;
        #pragma unroll
        for (int n = 0; n < NB; ++n) Cr[n * 16] = acc[m][n][r];
      }
  }
}

// ---------------- v blend + transpose to vt[h][hd][kv'] (kv permuted per 32-block) ----
// kv' column c within each 32-block holds actual kv = (c&1)*16 + (c>>1), so that
// attention's P-pack (p_t0, p_t1) lands in adjacent columns.
__global__ __launch_bounds__(256) void v_blend_tr(const float* __restrict__ Cv,
                                                  const float* __restrict__ v1,
                                                  const float* __restrict__ lambp,
                                                  short* __restrict__ vt) {
  __shared__ short lv[128][72];
  const int h = blockIdx.y, t0 = blockIdx.x * 128;
  const float lamb = *lambp;
  const int tid = threadIdx.x;
  #pragma unroll 4
  for (int it = 0; it < 32; ++it) {
    int e = it * 256 + tid;
    int tl = e >> 6, d = e & 63;
    float v = Cv[(size_t)(t0 + tl) * 1024 + h * 64 + d];
    float w = v1[(size_t)(t0 + tl) * 1024 + h * 64 + d];
    lv[tl][d] = f2bs((1.f - lamb) * v + lamb * w);
  }
  __syncthreads();
  #pragma unroll 4
  for (int it = 0; it < 32; ++it) {
    int e = it * 256 + tid;
    int d = e >> 7, tl = e & 127;
    int src = (tl & 96) + ((tl & 1) << 4) + ((tl >> 1) & 15);  // permuted source row
    vt[((size_t)h * 64 + d) * T_SEQ + t0 + tl] = lv[src][d];
  }
}

// ---------------- causal attention, split-KV, LDS-staged K/V (double-buffered) -------
// No online max needed (scores bounded by RMS norm): partials over kv strips combine
// by plain addition of accO and lsum -> split-KV grid (head, qgroup64, strip512).
// Partials stored compactly at slot = head*80 + b (b = linear job id 0..79).
__global__ __launch_bounds__(256) void attn(const short* __restrict__ qb,
                                            const short* __restrict__ kb,
                                            const short* __restrict__ vtp,
                                            float* __restrict__ part) {
  __shared__ __attribute__((aligned(16))) short Ks[2][4096];
  __shared__ __attribute__((aligned(16))) short Vs[2][4096];
  __shared__ __attribute__((aligned(16))) short p_lds[4][16][72];
  const int head = blockIdx.x & 15;
  const int b = blockIdx.x >> 4;  // 0..79
  int strip, qg;  // heavy-first (qg descending) within each strip class
  if (b < 32)      { strip = 0; qg = 31 - b; }
  else if (b < 56) { strip = 1; qg = 63 - b; }   // qg 31..8
  else if (b < 72) { strip = 2; qg = 87 - b; }   // qg 31..16
  else             { strip = 3; qg = 103 - b; }  // qg 31..24
  const int nt = min(8, qg + 1 - strip * 8);
  const int lane = threadIdx.x & 63, wid = threadIdx.x >> 6;
  const int lr = lane & 15, lg = lane >> 4;
  const int qt0 = qg * 64 + wid * 16;
  const short* Q = qb + (size_t)head * (T_SEQ * HD);
  const short* Kp = kb + (size_t)head * (T_SEQ * HD);
  const short* Vt = vtp + (size_t)head * (HD * T_SEQ);
  short (*P)[72] = p_lds[wid];

  bf16x8 aq0 = *(const bf16x8*)&Q[(size_t)(qt0 + lr) * HD + 8 * lg];
  bf16x8 aq1 = *(const bf16x8*)&Q[(size_t)(qt0 + lr) * HD + 32 + 8 * lg];
  f32x4 accO[4] = {};
  float lsum[4] = {0.f, 0.f, 0.f, 0.f};

  auto stage = [&](int buf, int jg) {
    const int kv0 = jg * 64;
    #pragma unroll
    for (int i = 0; i < 2; ++i) {
      int s = i * 256 + wid * 64 + lane;       // chunk id 0..511 (16B chunks)
      int row = s >> 3;                        // tile row 0..63
      int cG = (s & 7) ^ (row & 7);            // inverse-swizzled source chunk
      gload16(Kp + (size_t)(kv0 + row) * HD + cG * 8,
              &Ks[buf][(size_t)(i * 256 + wid * 64) * 8]);
      gload16(Vt + (size_t)row * T_SEQ + kv0 + cG * 8,
              &Vs[buf][(size_t)(i * 256 + wid * 64) * 8]);
    }
  };
  stage(0, strip * 8);
  for (int j = 0; j < nt; ++j) {
    const int jg = strip * 8 + j;
    __syncthreads();                            // drains vmcnt: buf[j&1] ready
    if (j + 1 < nt) stage((j + 1) & 1, jg + 1); // prefetch stays in flight
    const short* Kb = Ks[j & 1];
    const short* Vb = Vs[j & 1];
    f32x4 st[4];
    #pragma unroll
    for (int t = 0; t < 4; ++t) {
      int row = 16 * t + lr;
      int c0 = lg ^ (row & 7);
      bf16x8 k0 = *(const bf16x8*)&Kb[row * 64 + c0 * 8];
      bf16x8 k1 = *(const bf16x8*)&Kb[row * 64 + (c0 ^ 4) * 8];
      f32x4 s = {};
      s = __builtin_amdgcn_mfma_f32_16x16x32_bf16(aq0, k0, s, 0, 0, 0);
      s = __builtin_amdgcn_mfma_f32_16x16x32_bf16(aq1, k1, s, 0, 0, 0);
      st[t] = s;
    }
    if (jg == qg) {  // diagonal tile: causal mask (block-uniform branch)
      #pragma unroll
      for (int t = 0; t < 4; ++t)
        #pragma unroll
        for (int r = 0; r < 4; ++r)
          st[t][r] = (16 * t + lr > wid * 16 + 4 * lg + r) ? -1e30f : st[t][r];
    }
    #pragma unroll
    for (int r = 0; r < 4; ++r) {
      float p0 = __builtin_exp2f(st[0][r]);
      float p1 = __builtin_exp2f(st[1][r]);
      float p2 = __builtin_exp2f(st[2][r]);
      float p3 = __builtin_exp2f(st[3][r]);
      lsum[r] += (p0 + p1) + (p2 + p3);
      *(unsigned*)&P[4 * lg + r][2 * lr] = cvt_pk_bf16(p0, p1);
      *(unsigned*)&P[4 * lg + r][32 + 2 * lr] = cvt_pk_bf16(p2, p3);
    }
    asm volatile("s_waitcnt lgkmcnt(0)" ::: "memory");  // wave-private P roundtrip
    __builtin_amdgcn_sched_barrier(0);
    bf16x8 pa0 = *(const bf16x8*)&P[lr][8 * lg];
    bf16x8 pa1 = *(const bf16x8*)&P[lr][32 + 8 * lg];
    #pragma unroll
    for (int nv = 0; nv < 4; ++nv) {
      int row0 = nv * 16 + lr;
      int c0 = lg ^ (row0 & 7);
      bf16x8 v0 = *(const bf16x8*)&Vb[row0 * 64 + c0 * 8];
      bf16x8 v1 = *(const bf16x8*)&Vb[row0 * 64 + (c0 ^ 4) * 8];
      accO[nv] = __builtin_amdgcn_mfma_f32_16x16x32_bf16(pa0, v0, accO[nv], 0, 0, 0);
      accO[nv] = __builtin_amdgcn_mfma_f32_16x16x32_bf16(pa1, v1, accO[nv], 0, 0, 0);
    }
  }
  // write partials: 64x64 O block + 64 lsum, compact slot = head*80 + b
  float* pO = part + (size_t)(head * 80 + b) * 4160;
  float* pL = pO + 4096;
  #pragma unroll
  for (int r = 0; r < 4; ++r) {
    float sres = lsum[r];
    sres += __shfl_xor(sres, 1);
    sres += __shfl_xor(sres, 2);
    sres += __shfl_xor(sres, 4);
    sres += __shfl_xor(sres, 8);
    int row = wid * 16 + 4 * lg + r;
    #pragma unroll
    for (int nv = 0; nv < 4; ++nv)
      pO[row * 64 + nv * 16 + lr] = accO[nv][r];
    if (lr == 0) pL[row] = sres;
  }
}

// ---------------- combine split-KV partials, apply gate, write bf16 ----------------
__global__ __launch_bounds__(256) void attn_reduce(const float* __restrict__ part,
                                                   const float* __restrict__ gate,
                                                   short* __restrict__ ob) {
  const int head = blockIdx.x & 15;
  const int qg = blockIdx.x >> 4;
  const int ns = (qg >> 3) + 1;
  const int tid = threadIdx.x;
  const int row = tid >> 2, q4 = tid & 3;
  const int sbase[4] = {0, 32, 56, 72};  // strip -> b base (b = sbase[s] + 31 - qg)
  f32x4 o[4] = {};
  float l = 0.f;
  for (int s = 0; s < ns; ++s) {
    const float* pb = part + (size_t)(head * 80 + sbase[s] + 31 - qg) * 4160;
    #pragma unroll
    for (int c = 0; c < 4; ++c)
      o[c] += *(const f32x4*)&pb[row * 64 + q4 * 16 + c * 4];
    l += pb[4096 + row];
  }
  const int t = qg * 64 + row;
  const float gs = gate[t * 16 + head] / l;
  short* op = ob + (size_t)t * 1024 + head * 64 + q4 * 16;
  #pragma unroll
  for (int c = 0; c < 4; ++c) {
    bf16x4 w;
    w[0] = f2bs(o[c][0] * gs); w[1] = f2bs(o[c][1] * gs);
    w[2] = f2bs(o[c][2] * gs); w[3] = f2bs(o[c][3] * gs);
    *(bf16x4*)&op[c * 4] = w;
  }
}

extern "C" void kernel_launch(void* const* d_in, const int* in_sizes, int n_in,
                              void* d_out, int out_size, void* d_ws, size_t ws_size,
                              hipStream_t stream) {
  const float* x     = (const float*)d_in[0];
  const float* v1    = (const float*)d_in[1];
  const float* Wq    = (const float*)d_in[2];
  const float* Wk    = (const float*)d_in[3];
  const float* Wv    = (const float*)d_in[4];
  const float* Wproj = (const float*)d_in[5];
  const float* lamb  = (const float*)d_in[6];
  const float* Wgate = (const float*)d_in[7];
  float* out = (float*)d_out;

  char* ws = (char*)d_ws;
  short*  xb   = (short*)(ws);                      // 4MB (reused as ob after QKV GEMM)
  short*  wqkv = (short*)(ws + ((size_t)4  << 20)); // 6MB
  short*  wpj  = (short*)(ws + ((size_t)10 << 20)); // 2MB
  float*  Cv   = (float*)(ws + ((size_t)12 << 20)); // 8MB [T][1024] (v proj, f32)
  float*  part = Cv;                                 // 20.3MB, written AFTER Cv consumed
  float2* rope = (float2*)(ws + ((size_t)34 << 20)); // 512KB (above part's 32.3MB end)
  short*  qb   = (short*)(ws + ((size_t)36 << 20)); // 4MB
  short*  kb   = (short*)(ws + ((size_t)40 << 20)); // 4MB
  short*  vt   = (short*)(ws + ((size_t)44 << 20)); // 4MB
  float*  gate = (float*)(ws + ((size_t)48 << 20)); // 128KB
  short*  ob   = xb;

  cvt_all<<<6144, 256, 0, stream>>>(x, Wq, Wk, Wv, Wproj, xb, wqkv, wpj);
  gate_rope<<<(T_SEQ * NH) / 256, 256, 0, stream>>>(x, Wgate, gate, rope);
  gemm64<128, true><<<dim3(32, 24), 256, 0, stream>>>(xb, wqkv, Cv, qb, kb, rope,
                                                      3072, 1024);
  v_blend_tr<<<dim3(T_SEQ / 128, NH), 256, 0, stream>>>(Cv, v1, lamb, vt);
  attn<<<1280, 256, 0, stream>>>(qb, kb, vt, part);
  attn_reduce<<<512, 256, 0, stream>>>(part, gate, ob);
  gemm64<64, false><<<dim3(32, 16), 256, 0, stream>>>(ob, wpj, out, nullptr, nullptr,
                                                      nullptr, 1024, 1024);
  hipMemcpyAsync(out + (size_t)T_SEQ * 1024, v1,
                 (size_t)T_SEQ * 1024 * sizeof(float),
                 hipMemcpyDeviceToDevice, stream);
}

// Round 6
// 115.834 us; speedup vs baseline: 1.9284x; 1.0058x over previous
//
#include <hip/hip_runtime.h>
#include <hip/hip_bf16.h>

#define T_SEQ 2048
#define NH 16
#define HD 64
// 0.1 (attn scale) * log2(e) folded into q at norm time -> softmax uses exp2
#define SCALE_LOG2E 0.14426950408889634f

typedef __attribute__((ext_vector_type(8))) short bf16x8;
typedef __attribute__((ext_vector_type(4))) short bf16x4;
typedef __attribute__((ext_vector_type(4))) float f32x4;

__device__ __forceinline__ short f2bs(float f) {
  union { float f; unsigned u; } v; v.f = f;
  unsigned r = v.u + 0x7fffu + ((v.u >> 16) & 1u);
  return (short)(r >> 16);
}

__device__ __forceinline__ unsigned cvt_pk_bf16(float lo, float hi) {
  unsigned r;
  asm("v_cvt_pk_bf16_f32 %0, %1, %2" : "=v"(r) : "v"(lo), "v"(hi));
  return r;
}

__device__ __forceinline__ void gload16(const short* g, short* l) {
  __builtin_amdgcn_global_load_lds(
      (const __attribute__((address_space(1))) void*)g,
      (__attribute__((address_space(3))) void*)l, 16, 0, 0);
}

// ---------------- fused f32 -> bf16 convert (x, Wq|Wk|Wv, Wproj) ----------------
__global__ __launch_bounds__(256) void cvt_all(const float* __restrict__ x,
                                               const float* __restrict__ wq,
                                               const float* __restrict__ wk,
                                               const float* __restrict__ wv,
                                               const float* __restrict__ wp,
                                               short* __restrict__ xb,
                                               short* __restrict__ wqkv,
                                               short* __restrict__ wpj) {
  size_t i4 = (size_t)(blockIdx.x * 256 + threadIdx.x) * 4;  // over 6M elements
  const int seg = (int)(i4 >> 20);
  const size_t off = i4 & ((1u << 20) - 1);
  const float* src;
  short* dst;
  if (seg < 2)       { src = x + i4;   dst = xb + i4; }
  else if (seg == 2) { src = wq + off; dst = wqkv + off; }
  else if (seg == 3) { src = wk + off; dst = wqkv + (1u << 20) + off; }
  else if (seg == 4) { src = wv + off; dst = wqkv + (2u << 20) + off; }
  else               { src = wp + off; dst = wpj + off; }
  float4 v = *reinterpret_cast<const float4*>(src);
  bf16x4 o; o[0] = f2bs(v.x); o[1] = f2bs(v.y); o[2] = f2bs(v.z); o[3] = f2bs(v.w);
  *reinterpret_cast<bf16x4*>(dst) = o;
}

// -------- gate: sigmoid(x[:, :12] @ Wgate^T); also fills rope table (cos,sin) --------
__global__ __launch_bounds__(256) void gate_rope(const float* __restrict__ x,
                                                 const float* __restrict__ Wg,
                                                 float* __restrict__ gate,
                                                 float2* __restrict__ rope) {
  int id = blockIdx.x * 256 + threadIdx.x;  // t*16 + h, 32768 total
  int t = id >> 4, h = id & 15;
  float acc = 0.f;
  #pragma unroll
  for (int i = 0; i < 12; ++i) acc += x[(size_t)t * 1024 + i] * Wg[h * 12 + i];
  gate[id] = 1.f / (1.f + __expf(-acc));
  // rope[t][p]: 65536 entries, 2 per thread
  #pragma unroll
  for (int j = 0; j < 2; ++j) {
    int e = id * 2 + j;
    int tt = e >> 5, p = e & 31;
    float invf = __builtin_exp2f(-0.41524101186092f * (float)p);
    float s, c;
    sincosf((float)tt * invf, &s, &c);
    rope[e] = make_float2(c, s);
  }
}

// ---------------- GEMM: C[M][N] = A[M][K] * B[N][K]^T (bf16 in) ----------------
// BM=64 x BN tile, BK=32, 4 waves (2x2); DOUBLE-BUFFERED global_load_lds staging:
// one barrier per K-step, prefetch for step k+1 issued right after the barrier so
// its HBM/L2 latency hides under step k's ds_read+MFMA (T3 minimum-2-phase recipe;
// round-5 structure drained vmcnt immediately after issue -> latency fully exposed).
// QKV=true: fused epilogue. bn<2048 -> RMSNorm+RoPE -> bf16 qb/kb [h][t][64];
//           bn>=2048 -> plain f32 Cv (cols bn-2048). QKV=false: plain f32 C.
template <int BN, bool QKV>
__global__ __launch_bounds__(256) void gemm64(const short* __restrict__ A,
                                              const short* __restrict__ B,
                                              float* __restrict__ C,
                                              short* __restrict__ qb,
                                              short* __restrict__ kb,
                                              const float2* __restrict__ rope,
                                              int N, int K) {
  constexpr int NB = BN / 32;  // fragments per wave in N
  __shared__ __attribute__((aligned(16))) short As[2][4][64][8];
  __shared__ __attribute__((aligned(16))) short Bs[2][4][BN][8];
  const int tid = threadIdx.x;
  const int lane = tid & 63, wid = tid >> 6;
  const int lr = lane & 15, lg = lane >> 4;
  const int wm = (wid >> 1) * 32, wn = (wid & 1) * (BN / 2);
  const int bm = blockIdx.x * 64, bn = blockIdx.y * BN;
  // wave `wid` stages k-slot `wid` (k offset wid*8)
  const short* Ap = A + (size_t)(bm + lane) * K + wid * 8;
  const short* Bp = B + (size_t)(bn + lane) * K + wid * 8;
  f32x4 acc[2][NB] = {};
  auto stage = [&](int buf, int k0) {
    gload16(Ap + k0, &As[buf][wid][0][0]);
    #pragma unroll
    for (int g = 0; g < BN / 64; ++g)
      gload16(Bp + (size_t)(64 * g) * K + k0, &Bs[buf][wid][64 * g][0]);
  };
  stage(0, 0);
  int cur = 0;
  for (int k0 = 0; k0 < K; k0 += 32) {
    __syncthreads();  // drains prefetch vmcnt -> buf[cur] ready; prev reads done
    if (k0 + 32 < K) stage(cur ^ 1, k0 + 32);  // flies during this step's compute
    bf16x8 af[2], bfr[NB];
    #pragma unroll
    for (int m = 0; m < 2; ++m) af[m] = *(const bf16x8*)&As[cur][lg][wm + m * 16 + lr][0];
    #pragma unroll
    for (int n = 0; n < NB; ++n) bfr[n] = *(const bf16x8*)&Bs[cur][lg][wn + n * 16 + lr][0];
    #pragma unroll
    for (int m = 0; m < 2; ++m)
      #pragma unroll
      for (int n = 0; n < NB; ++n)
        acc[m][n] = __builtin_amdgcn_mfma_f32_16x16x32_bf16(af[m], bfr[n], acc[m][n], 0, 0, 0);
    cur ^= 1;
  }
  if constexpr (QKV) {
    if (bn < 2048) {  // q or k head: wave cols = exactly one head
      const bool isq = (bn < 1024);
      short* dst = isq ? qb : kb;
      const int h = ((bn + wn) & 1023) >> 6;
      #pragma unroll
      for (int m = 0; m < 2; ++m)
        #pragma unroll
        for (int r = 0; r < 4; ++r) {
          const int t = bm + wm + m * 16 + 4 * lg + r;
          float ss = acc[m][0][r] * acc[m][0][r] + acc[m][1][r] * acc[m][1][r]
                   + acc[m][2][r] * acc[m][2][r] + acc[m][3][r] * acc[m][3][r];
          ss += __shfl_xor(ss, 1);
          ss += __shfl_xor(ss, 2);
          ss += __shfl_xor(ss, 4);
          ss += __shfl_xor(ss, 8);
          const float rms = rsqrtf(ss * (1.f / 64.f) + 1e-6f);
          short* row = dst + ((size_t)h * T_SEQ + t) * 64;
          #pragma unroll
          for (int n2 = 0; n2 < 2; ++n2) {  // rope pair (d, d+32) = (n2, n2+2)
            float x1 = acc[m][n2][r] * rms, x2 = acc[m][n2 + 2][r] * rms;
            float2 cs = rope[t * 32 + n2 * 16 + lr];
            float y1 = x1 * cs.x + x2 * cs.y;
            float y2 = x2 * cs.x - x1 * cs.y;
            if (isq) { y1 *= SCALE_LOG2E; y2 *= SCALE_LOG2E; }
            row[n2 * 16 + lr] = f2bs(y1);
            row[32 + n2 * 16 + lr] = f2bs(y2);
          }
        }
    } else {  // v region -> plain f32 Cv [t][1024]
      #pragma unroll
      for (int m = 0; m < 2; ++m)
        #pragma unroll
        for (int r = 0; r < 4; ++r) {
          const int t = bm + wm + m * 16 + 4 * lg + r;
          float* Cr = C + (size_t)t * 1024 + (bn - 2048) + wn + lr;
          #pragma unroll
          for (int n = 0; n < NB; ++n) Cr[n * 16] = acc[m][n][r];
        }
    }
  } else {
    #pragma unroll
    for (int m = 0; m < 2; ++m)
      #pragma unroll
      for (int r = 0; r < 4; ++r) {
        const int t = bm + wm + m * 16 + 4 * lg + r;
        float* Cr = C + (size_t)t * N + bn + wn + lr;
        #pragma unroll
        for (int n = 0; n < NB; ++n) Cr[n * 16] = acc[m][n][r];
      }
  }
}

// ---------------- v blend + transpose to vt[h][hd][kv'] (kv permuted per 32-block) ----
// kv' column c within each 32-block holds actual kv = (c&1)*16 + (c>>1), so that
// attention's P-pack (p_t0, p_t1) lands in adjacent columns.
__global__ __launch_bounds__(256) void v_blend_tr(const float* __restrict__ Cv,
                                                  const float* __restrict__ v1,
                                                  const float* __restrict__ lambp,
                                                  short* __restrict__ vt) {
  __shared__ short lv[128][72];
  const int h = blockIdx.y, t0 = blockIdx.x * 128;
  const float lamb = *lambp;
  const int tid = threadIdx.x;
  #pragma unroll 4
  for (int it = 0; it < 32; ++it) {
    int e = it * 256 + tid;
    int tl = e >> 6, d = e & 63;
    float v = Cv[(size_t)(t0 + tl) * 1024 + h * 64 + d];
    float w = v1[(size_t)(t0 + tl) * 1024 + h * 64 + d];
    lv[tl][d] = f2bs((1.f - lamb) * v + lamb * w);
  }
  __syncthreads();
  #pragma unroll 4
  for (int it = 0; it < 32; ++it) {
    int e = it * 256 + tid;
    int d = e >> 7, tl = e & 127;
    int src = (tl & 96) + ((tl & 1) << 4) + ((tl >> 1) & 15);  // permuted source row
    vt[((size_t)h * 64 + d) * T_SEQ + t0 + tl] = lv[src][d];
  }
}

// ---------------- causal attention, split-KV, LDS-staged K/V (double-buffered) -------
// No online max needed (scores bounded by RMS norm): partials over kv strips combine
// by plain addition of accO and lsum -> split-KV grid (head, qgroup64, strip512).
// Partials stored compactly at slot = head*80 + b (b = linear job id 0..79).
__global__ __launch_bounds__(256) void attn(const short* __restrict__ qb,
                                            const short* __restrict__ kb,
                                            const short* __restrict__ vtp,
                                            float* __restrict__ part) {
  __shared__ __attribute__((aligned(16))) short Ks[2][4096];
  __shared__ __attribute__((aligned(16))) short Vs[2][4096];
  __shared__ __attribute__((aligned(16))) short p_lds[4][16][72];
  const int head = blockIdx.x & 15;
  const int b = blockIdx.x >> 4;  // 0..79
  int strip, qg;  // heavy-first (qg descending) within each strip class
  if (b < 32)      { strip = 0; qg = 31 - b; }
  else if (b < 56) { strip = 1; qg = 63 - b; }   // qg 31..8
  else if (b < 72) { strip = 2; qg = 87 - b; }   // qg 31..16
  else             { strip = 3; qg = 103 - b; }  // qg 31..24
  const int nt = min(8, qg + 1 - strip * 8);
  const int lane = threadIdx.x & 63, wid = threadIdx.x >> 6;
  const int lr = lane & 15, lg = lane >> 4;
  const int qt0 = qg * 64 + wid * 16;
  const short* Q = qb + (size_t)head * (T_SEQ * HD);
  const short* Kp = kb + (size_t)head * (T_SEQ * HD);
  const short* Vt = vtp + (size_t)head * (HD * T_SEQ);
  short (*P)[72] = p_lds[wid];

  bf16x8 aq0 = *(const bf16x8*)&Q[(size_t)(qt0 + lr) * HD + 8 * lg];
  bf16x8 aq1 = *(const bf16x8*)&Q[(size_t)(qt0 + lr) * HD + 32 + 8 * lg];
  f32x4 accO[4] = {};
  float lsum[4] = {0.f, 0.f, 0.f, 0.f};

  auto stage = [&](int buf, int jg) {
    const int kv0 = jg * 64;
    #pragma unroll
    for (int i = 0; i < 2; ++i) {
      int s = i * 256 + wid * 64 + lane;       // chunk id 0..511 (16B chunks)
      int row = s >> 3;                        // tile row 0..63
      int cG = (s & 7) ^ (row & 7);            // inverse-swizzled source chunk
      gload16(Kp + (size_t)(kv0 + row) * HD + cG * 8,
              &Ks[buf][(size_t)(i * 256 + wid * 64) * 8]);
      gload16(Vt + (size_t)row * T_SEQ + kv0 + cG * 8,
              &Vs[buf][(size_t)(i * 256 + wid * 64) * 8]);
    }
  };
  stage(0, strip * 8);
  for (int j = 0; j < nt; ++j) {
    const int jg = strip * 8 + j;
    __syncthreads();                            // drains vmcnt: buf[j&1] ready
    if (j + 1 < nt) stage((j + 1) & 1, jg + 1); // prefetch stays in flight
    const short* Kb = Ks[j & 1];
    const short* Vb = Vs[j & 1];
    f32x4 st[4];
    #pragma unroll
    for (int t = 0; t < 4; ++t) {
      int row = 16 * t + lr;
      int c0 = lg ^ (row & 7);
      bf16x8 k0 = *(const bf16x8*)&Kb[row * 64 + c0 * 8];
      bf16x8 k1 = *(const bf16x8*)&Kb[row * 64 + (c0 ^ 4) * 8];
      f32x4 s = {};
      s = __builtin_amdgcn_mfma_f32_16x16x32_bf16(aq0, k0, s, 0, 0, 0);
      s = __builtin_amdgcn_mfma_f32_16x16x32_bf16(aq1, k1, s, 0, 0, 0);
      st[t] = s;
    }
    if (jg == qg) {  // diagonal tile: causal mask (block-uniform branch)
      #pragma unroll
      for (int t = 0; t < 4; ++t)
        #pragma unroll
        for (int r = 0; r < 4; ++r)
          st[t][r] = (16 * t + lr > wid * 16 + 4 * lg + r) ? -1e30f : st[t][r];
    }
    #pragma unroll
    for (int r = 0; r < 4; ++r) {
      float p0 = __builtin_exp2f(st[0][r]);
      float p1 = __builtin_exp2f(st[1][r]);
      float p2 = __builtin_exp2f(st[2][r]);
      float p3 = __builtin_exp2f(st[3][r]);
      lsum[r] += (p0 + p1) + (p2 + p3);
      *(unsigned*)&P[4 * lg + r][2 * lr] = cvt_pk_bf16(p0, p1);
      *(unsigned*)&P[4 * lg + r][32 + 2 * lr] = cvt_pk_bf16(p2, p3);
    }
    asm volatile("s_waitcnt lgkmcnt(0)" ::: "memory");  // wave-private P roundtrip
    __builtin_amdgcn_sched_barrier(0);
    bf16x8 pa0 = *(const bf16x8*)&P[lr][8 * lg];
    bf16x8 pa1 = *(const bf16x8*)&P[lr][32 + 8 * lg];
    #pragma unroll
    for (int nv = 0; nv < 4; ++nv) {
      int row0 = nv * 16 + lr;
      int c0 = lg ^ (row0 & 7);
      bf16x8 v0 = *(const bf16x8*)&Vb[row0 * 64 + c0 * 8];
      bf16x8 v1 = *(const bf16x8*)&Vb[row0 * 64 + (c0 ^ 4) * 8];
      accO[nv] = __builtin_amdgcn_mfma_f32_16x16x32_bf16(pa0, v0, accO[nv], 0, 0, 0);
      accO[nv] = __builtin_amdgcn_mfma_f32_16x16x32_bf16(pa1, v1, accO[nv], 0, 0, 0);
    }
  }
  // write partials: 64x64 O block + 64 lsum, compact slot = head*80 + b
  float* pO = part + (size_t)(head * 80 + b) * 4160;
  float* pL = pO + 4096;
  #pragma unroll
  for (int r = 0; r < 4; ++r) {
    float sres = lsum[r];
    sres += __shfl_xor(sres, 1);
    sres += __shfl_xor(sres, 2);
    sres += __shfl_xor(sres, 4);
    sres += __shfl_xor(sres, 8);
    int row = wid * 16 + 4 * lg + r;
    #pragma unroll
    for (int nv = 0; nv < 4; ++nv)
      pO[row * 64 + nv * 16 + lr] = accO[nv][r];
    if (lr == 0) pL[row] = sres;
  }
}

// ---------------- combine split-KV partials, apply gate, write bf16 ----------------
__global__ __launch_bounds__(256) void attn_reduce(const float* __restrict__ part,
                                                   const float* __restrict__ gate,
                                                   short* __restrict__ ob) {
  const int head = blockIdx.x & 15;
  const int qg = blockIdx.x >> 4;
  const int ns = (qg >> 3) + 1;
  const int tid = threadIdx.x;
  const int row = tid >> 2, q4 = tid & 3;
  const int sbase[4] = {0, 32, 56, 72};  // strip -> b base (b = sbase[s] + 31 - qg)
  f32x4 o[4] = {};
  float l = 0.f;
  for (int s = 0; s < ns; ++s) {
    const float* pb = part + (size_t)(head * 80 + sbase[s] + 31 - qg) * 4160;
    #pragma unroll
    for (int c = 0; c < 4; ++c)
      o[c] += *(const f32x4*)&pb[row * 64 + q4 * 16 + c * 4];
    l += pb[4096 + row];
  }
  const int t = qg * 64 + row;
  const float gs = gate[t * 16 + head] / l;
  short* op = ob + (size_t)t * 1024 + head * 64 + q4 * 16;
  #pragma unroll
  for (int c = 0; c < 4; ++c) {
    bf16x4 w;
    w[0] = f2bs(o[c][0] * gs); w[1] = f2bs(o[c][1] * gs);
    w[2] = f2bs(o[c][2] * gs); w[3] = f2bs(o[c][3] * gs);
    *(bf16x4*)&op[c * 4] = w;
  }
}

extern "C" void kernel_launch(void* const* d_in, const int* in_sizes, int n_in,
                              void* d_out, int out_size, void* d_ws, size_t ws_size,
                              hipStream_t stream) {
  const float* x     = (const float*)d_in[0];
  const float* v1    = (const float*)d_in[1];
  const float* Wq    = (const float*)d_in[2];
  const float* Wk    = (const float*)d_in[3];
  const float* Wv    = (const float*)d_in[4];
  const float* Wproj = (const float*)d_in[5];
  const float* lamb  = (const float*)d_in[6];
  const float* Wgate = (const float*)d_in[7];
  float* out = (float*)d_out;

  char* ws = (char*)d_ws;
  short*  xb   = (short*)(ws);                      // 4MB (reused as ob after QKV GEMM)
  short*  wqkv = (short*)(ws + ((size_t)4  << 20)); // 6MB
  short*  wpj  = (short*)(ws + ((size_t)10 << 20)); // 2MB
  float*  Cv   = (float*)(ws + ((size_t)12 << 20)); // 8MB [T][1024] (v proj, f32)
  float*  part = Cv;                                 // 20.3MB, written AFTER Cv consumed
  float2* rope = (float2*)(ws + ((size_t)34 << 20)); // 512KB (above part's 32.3MB end)
  short*  qb   = (short*)(ws + ((size_t)36 << 20)); // 4MB
  short*  kb   = (short*)(ws + ((size_t)40 << 20)); // 4MB
  short*  vt   = (short*)(ws + ((size_t)44 << 20)); // 4MB
  float*  gate = (float*)(ws + ((size_t)48 << 20)); // 128KB
  short*  ob   = xb;

  cvt_all<<<6144, 256, 0, stream>>>(x, Wq, Wk, Wv, Wproj, xb, wqkv, wpj);
  gate_rope<<<(T_SEQ * NH) / 256, 256, 0, stream>>>(x, Wgate, gate, rope);
  gemm64<128, true><<<dim3(32, 24), 256, 0, stream>>>(xb, wqkv, Cv, qb, kb, rope,
                                                      3072, 1024);
  v_blend_tr<<<dim3(T_SEQ / 128, NH), 256, 0, stream>>>(Cv, v1, lamb, vt);
  attn<<<1280, 256, 0, stream>>>(qb, kb, vt, part);
  attn_reduce<<<512, 256, 0, stream>>>(part, gate, ob);
  gemm64<64, false><<<dim3(32, 16), 256, 0, stream>>>(ob, wpj, out, nullptr, nullptr,
                                                      nullptr, 1024, 1024);
  hipMemcpyAsync(out + (size_t)T_SEQ * 1024, v1,
                 (size_t)T_SEQ * 1024 * sizeof(float),
                 hipMemcpyDeviceToDevice, stream);
}